// Round 9
// baseline (791.250 us; speedup 1.0000x reference)
//
#include <hip/hip_runtime.h>
#include <hip/hip_bf16.h>
#include <math.h>

#define NN 50000
#define NE 500000
#define KSEL 25000
#define NB_E 391   // ceil(NN/128) dst buckets

typedef unsigned int u32;
typedef unsigned long long u64;
typedef short bf16x8 __attribute__((ext_vector_type(8)));   // 8 bf16 raw bits (4 VGPRs)
typedef float f32x4 __attribute__((ext_vector_type(4)));

__device__ __forceinline__ unsigned short f2bf(float f) {   // RNE
    u32 u = __float_as_uint(f);
    u32 r = (u + 0x7fffu + ((u >> 16) & 1u)) >> 16;
    return (unsigned short)r;
}
// dot of two u32s each holding 2 bf16 (lo = even elem, hi = odd elem)
__device__ __forceinline__ float dpair(u32 a, u32 q) {
    float al = __uint_as_float(a << 16), ah = __uint_as_float(a & 0xffff0000u);
    float ql = __uint_as_float(q << 16), qh = __uint_as_float(q & 0xffff0000u);
    return al * ql + ah * qh;
}

// ---------------- precompute ----------------

// h (f32) -> hb (bf16 bits)
__global__ __launch_bounds__(256) void k_cast(const float* __restrict__ h, unsigned short* __restrict__ hb) {
    int i = blockIdx.x * 256 + threadIdx.x;   // 1.6M threads, 4 elems each
    float4 v = *(const float4*)(h + (size_t)i * 4);
    ushort4 o;
    o.x = f2bf(v.x); o.y = f2bf(v.y); o.z = f2bf(v.z); o.w = f2bf(v.w);
    *(ushort4*)(hb + (size_t)i * 4) = o;
}

// panel0 of Gt: Gt[m][k] = Wqk[k][m] = sum_c Wq[c,k]*Wk[c,m]; bqk[m] = sum_c bq[c]*Wk[c,m]
__global__ __launch_bounds__(128) void k_wqk(const float* __restrict__ Wq, const float* __restrict__ Wk,
                                             const float* __restrict__ bq,
                                             unsigned short* __restrict__ Gt, float* __restrict__ bqk) {
    int k = blockIdx.x;   // 0..127
    int m = threadIdx.x;  // 0..127
    float acc = 0.f;
    for (int c = 0; c < 128; ++c) acc += Wq[c * 128 + k] * Wk[c * 128 + m];
    Gt[(size_t)m * 128 + k] = f2bf(acc);
    if (k == 0) {
        float b = 0.f;
        for (int c = 0; c < 128; ++c) b += bq[c] * Wk[c * 128 + m];
        bqk[m] = b;
    }
}

// Gt panels 1-4 (W0a,W1a,W0b,W1b transposed) + wvecs
// wvecs: wa0[0:128] wa1[128:256] wb0[256:384] wb1[384:512] wkn[512:640] bkbq[640]
__global__ void k_prep(const float* __restrict__ Wb, const float* __restrict__ Wq,
                       const float* __restrict__ bq, const float* __restrict__ bk,
                       const float* __restrict__ Wv,
                       unsigned short* __restrict__ Gt, float* __restrict__ wvecs) {
    int idx = blockIdx.x * blockDim.x + threadIdx.x;
    if (idx < 65536) {
        int p = idx >> 14, rem = idx & 16383;
        int c = rem >> 7, k = rem & 127;
        float v;
        if (p == 0)      v = Wb[k * 128 + c];                    // W0a -> panel1
        else if (p == 1) v = Wb[32768 + k * 128 + c];            // W1a -> panel2
        else if (p == 2) v = Wb[16384 + k * 128 + c];            // W0b -> panel3
        else             v = Wb[49152 + k * 128 + c];            // W1b -> panel4
        Gt[(size_t)((p + 1) * 128 + c) * 128 + k] = f2bf(v);
    } else {
        int i = idx - 65536;
        if (i < 128)      { float s = 0; for (int m = 0; m < 128; ++m) s += Wb[i * 128 + m] * Wv[m]; wvecs[i] = s; }
        else if (i < 256) { int j = i - 128; float s = 0; for (int m = 0; m < 128; ++m) s += Wb[32768 + j * 128 + m] * Wv[m]; wvecs[i] = s; }
        else if (i < 384) { int j = i - 256; float s = 0; for (int m = 0; m < 128; ++m) s += Wb[(128 + j) * 128 + m] * Wv[m]; wvecs[i] = s; }
        else if (i < 512) { int j = i - 384; float s = 0; for (int m = 0; m < 128; ++m) s += Wb[32768 + (128 + j) * 128 + m] * Wv[m]; wvecs[i] = s; }
        else if (i < 640) { int j = i - 512; float s = 0; for (int c = 0; c < 128; ++c) s += bk[c] * Wq[c * 128 + j]; wvecs[i] = s; }
        else if (i == 640) { float s = 0; for (int c = 0; c < 128; ++c) s += bk[c] * bq[c]; wvecs[640] = s; }
    }
}

// ---------------- fused node GEMM: Y = hb @ G (128x640), bf16 MFMA, no LDS ----------------
__global__ __launch_bounds__(256) void k_mfma(const unsigned short* __restrict__ hb,
                                              const unsigned short* __restrict__ Gt,
                                              const float* __restrict__ bqk,
                                              unsigned short* __restrict__ q2b,
                                              unsigned short* __restrict__ a01b,
                                              unsigned short* __restrict__ w0b,
                                              unsigned short* __restrict__ w1b) {
    int t = threadIdx.x;
    int w = t >> 6, l = t & 63;
    int lr = l & 15, lg = l >> 4;               // A: row=lr, k-group=lg ; C/D: col=lr, row-group=lg
    int mb = blockIdx.x * 128;
    int panel = blockIdx.y;
    int rowbase = mb + w * 32;

    bf16x8 afr[2][4];
#pragma unroll
    for (int rt = 0; rt < 2; ++rt)
#pragma unroll
        for (int kk = 0; kk < 4; ++kk) {
            int row = rowbase + rt * 16 + lr;
            if (row >= NN) row = NN - 1;        // clamp; stores are guarded
            afr[rt][kk] = *reinterpret_cast<const bf16x8*>(hb + (size_t)row * 128 + kk * 32 + lg * 8);
        }

    f32x4 acc[2][8];
#pragma unroll
    for (int rt = 0; rt < 2; ++rt)
#pragma unroll
        for (int ct = 0; ct < 8; ++ct) acc[rt][ct] = (f32x4){0.f, 0.f, 0.f, 0.f};

#pragma unroll
    for (int ct = 0; ct < 8; ++ct) {
#pragma unroll
        for (int kk = 0; kk < 4; ++kk) {
            int gcol = panel * 128 + ct * 16 + lr;
            bf16x8 bfr = *reinterpret_cast<const bf16x8*>(Gt + (size_t)gcol * 128 + kk * 32 + lg * 8);
            acc[0][ct] = __builtin_amdgcn_mfma_f32_16x16x32_bf16(afr[0][kk], bfr, acc[0][ct], 0, 0, 0);
            acc[1][ct] = __builtin_amdgcn_mfma_f32_16x16x32_bf16(afr[1][kk], bfr, acc[1][ct], 0, 0, 0);
        }
    }

#pragma unroll
    for (int rt = 0; rt < 2; ++rt)
#pragma unroll
        for (int ct = 0; ct < 8; ++ct)
#pragma unroll
            for (int r = 0; r < 4; ++r) {
                int row = rowbase + rt * 16 + lg * 4 + r;
                if (row >= NN) continue;
                int col = ct * 16 + lr;
                float v = acc[rt][ct][r];
                if (panel == 0) {
                    q2b[(size_t)row * 128 + col] = f2bf(v + bqk[col]);
                } else if (panel == 1) {
                    a01b[(size_t)row * 256 + col] = f2bf(v);
                } else if (panel == 2) {
                    a01b[(size_t)row * 256 + 128 + col] = f2bf(v);
                } else if (panel == 3) {
                    w0b[(size_t)row * 128 + col] = f2bf(v);
                } else {
                    w1b[(size_t)row * 128 + col] = f2bf(v);
                }
            }
}

// t0[n] = w0[n]·q2[n], t1[n] = w1[n]·q2[n]  (1 wave per node)
__global__ __launch_bounds__(256) void k_tdot(const unsigned short* __restrict__ q2b,
                                              const unsigned short* __restrict__ w0b,
                                              const unsigned short* __restrict__ w1b,
                                              float* __restrict__ TT) {
    int n = blockIdx.x * 4 + (threadIdx.x >> 6);
    int lane = threadIdx.x & 63;
    u32 qw = ((const u32*)(q2b + (size_t)n * 128))[lane];
    u32 w0 = ((const u32*)(w0b + (size_t)n * 128))[lane];
    u32 w1 = ((const u32*)(w1b + (size_t)n * 128))[lane];
    float t0 = dpair(w0, qw);
    float t1 = dpair(w1, qw);
    for (int off = 32; off; off >>= 1) {
        t0 += __shfl_xor(t0, off);
        t1 += __shfl_xor(t1, off);
    }
    if (lane == 0) {
        TT[(size_t)n * 4 + 0] = t0;
        TT[(size_t)n * 4 + 1] = t1;
    }
}

// per-node scalars: av0,av1,bv0,bv1 (NS), kn (TT.z), self_y  (f32 h, exact)
__global__ void k_scal(const float* __restrict__ h, const float* __restrict__ wvecs,
                       const float* __restrict__ coeff, const float* __restrict__ bvp,
                       float* __restrict__ NS, float* __restrict__ TT, float* __restrict__ selfy) {
    int gid = blockIdx.x * blockDim.x + threadIdx.x;
    int wid = gid >> 6, lane = gid & 63;
    if (wid >= NN) return;
    const float* hrow = h + (size_t)wid * 128;
    float2 hv = *(const float2*)(hrow + lane * 2);
    float2 w0 = *(const float2*)(wvecs + 0 + lane * 2);
    float2 w1 = *(const float2*)(wvecs + 128 + lane * 2);
    float2 w2 = *(const float2*)(wvecs + 256 + lane * 2);
    float2 w3 = *(const float2*)(wvecs + 384 + lane * 2);
    float2 w4 = *(const float2*)(wvecs + 512 + lane * 2);
    float p0 = hv.x * w0.x + hv.y * w0.y;
    float p1 = hv.x * w1.x + hv.y * w1.y;
    float p2 = hv.x * w2.x + hv.y * w2.y;
    float p3 = hv.x * w3.x + hv.y * w3.y;
    float p4 = hv.x * w4.x + hv.y * w4.y;
    for (int off = 32; off; off >>= 1) {
        p0 += __shfl_xor(p0, off);
        p1 += __shfl_xor(p1, off);
        p2 += __shfl_xor(p2, off);
        p3 += __shfl_xor(p3, off);
        p4 += __shfl_xor(p4, off);
    }
    if (lane == 0) {
        float kn = p4 + wvecs[640];
        float c40 = coeff[8], c41 = coeff[9], bv = bvp[0];
        NS[(size_t)wid * 4 + 0] = p0;
        NS[(size_t)wid * 4 + 1] = p1;
        NS[(size_t)wid * 4 + 2] = p2;
        NS[(size_t)wid * 4 + 3] = p3;
        TT[(size_t)wid * 4 + 2] = kn;
        selfy[wid] = c40 * (p0 + p2) + c41 * (p1 + p3) + bv;
    }
}

// ---------------- edge sort by dst bucket (d>>7): hist -> scan -> scatter ----------------

__global__ void k_ehist(const int* __restrict__ dst, u32* __restrict__ ecnt) {
    int e = blockIdx.x * 256 + threadIdx.x;
    if (e < NE) atomicAdd(&ecnt[((u32)dst[e]) >> 7], 1u);
}

__global__ __launch_bounds__(512) void k_escan(const u32* __restrict__ ecnt, u32* __restrict__ eoff) {
    __shared__ u32 ws[8];
    int t = threadIdx.x;
    u32 x = (t < NB_E) ? ecnt[t] : 0;
    u32 v = x;
    int lane = t & 63;
    for (int o = 1; o < 64; o <<= 1) { u32 n = __shfl_up(v, o); if (lane >= o) v += n; }
    int w = t >> 6;
    if (lane == 63) ws[w] = v;
    __syncthreads();
    if (t == 0) { u32 r = 0; for (int i = 0; i < 8; ++i) { u32 q = ws[i]; ws[i] = r; r += q; } }
    __syncthreads();
    v += ws[w];
    if (t <= NB_E) eoff[t] = v - x;   // exclusive; t==NB_E gives total
}

__global__ void k_escat(const int* __restrict__ src, const int* __restrict__ dst,
                        const int* __restrict__ et, const u32* __restrict__ eoff,
                        u32* __restrict__ ecnt2, u64* __restrict__ EP) {
    int e = blockIdx.x * 256 + threadIdx.x;
    if (e >= NE) return;
    u32 d = (u32)dst[e];
    u32 b = d >> 7;
    u32 pos = eoff[b] + atomicAdd(&ecnt2[b], 1u);
    EP[pos] = (u64)(u32)src[e] | ((u64)d << 16) | ((u64)(u32)et[e] << 32);
}

// ---------------- edge kernel: bf16, d-sorted packed edges, 2 edges/wave ----------------
__global__ __launch_bounds__(256) void k_edge(const unsigned short* __restrict__ a01b,
                                              const unsigned short* __restrict__ q2b,
                                              const u64* __restrict__ EP,
                                              const float* __restrict__ NS, const float* __restrict__ TT,
                                              const float* __restrict__ coeff, const float* __restrict__ bvp,
                                              float* __restrict__ acc) {
    int tid = threadIdx.x;
    int e = blockIdx.x * 8 + (tid >> 5);        // 8 edges per 256-thr block (exact: NE/8 blocks)
    int lane = tid & 63;
    int l5 = tid & 31;
    int g = l5 >> 3, sub = l5 & 7;              // 4 dot groups of 8 lanes per edge
    u64 wrd = EP[e];
    int s = (int)(wrd & 0xFFFF);
    int d = (int)((wrd >> 16) & 0xFFFF);
    int ety = (int)((wrd >> 32) & 0x7);
    int r1 = (g < 2) ? s : d;
    int r2 = (g < 2) ? d : s;
    const u32* ap = (const u32*)(a01b + (size_t)r1 * 256 + (g & 1) * 128) + sub * 8;
    const u32* qp = (const u32*)(q2b + (size_t)r2 * 128) + sub * 8;
    uint4 A0 = *(const uint4*)ap, A1 = *(const uint4*)(ap + 4);
    uint4 Q0 = *(const uint4*)qp, Q1 = *(const uint4*)(qp + 4);
    float p = dpair(A0.x, Q0.x) + dpair(A0.y, Q0.y) + dpair(A0.z, Q0.z) + dpair(A0.w, Q0.w) +
              dpair(A1.x, Q1.x) + dpair(A1.y, Q1.y) + dpair(A1.z, Q1.z) + dpair(A1.w, Q1.w);
    p += __shfl_xor(p, 4);
    p += __shfl_xor(p, 2);
    p += __shfl_xor(p, 1);
    float mate = __shfl(p, (lane + 8) & 63);    // lane0<-8 (d1 in), lane16<-24 (d1 out), +32 for edge B
    if ((l5 & 15) == 0) {
        bool outdir = (l5 == 16);
        int agg = outdir ? s : d;
        int oth = outdir ? d : s;
        float c0 = coeff[ety * 2], c1 = coeff[ety * 2 + 1];
        float4 tt = *(const float4*)(TT + (size_t)agg * 4);
        float4 nsO = *(const float4*)(NS + (size_t)oth * 4);
        float4 nsA = *(const float4*)(NS + (size_t)agg * 4);
        float raw = c0 * (p + tt.x) + c1 * (mate + tt.y) + tt.z;
        float xc = fminf(fmaxf(raw * 0.08838834764831845f, -10.f), 10.f);
        float sc = expf(xc);
        float nv = c0 * (nsO.x + nsA.z) + c1 * (nsO.y + nsA.w) + bvp[0];
        float* wacc = acc + (size_t)(outdir ? 2 : 0) * NN;
        float* zacc = acc + (size_t)(outdir ? 3 : 1) * NN;
        atomicAdd(&wacc[agg], sc * nv);
        atomicAdd(&zacc[agg], sc);
    }
}

// ---------------- y, key, ranking, selection, output ----------------

__global__ void k_y(const float* __restrict__ acc, const float* __restrict__ selfy,
                    float* __restrict__ y, u32* __restrict__ key, u32* __restrict__ hist) {
    int i = blockIdx.x * blockDim.x + threadIdx.x;
    if (i >= NN) return;
    float win = acc[i], zin = acc[NN + i], wout = acc[2 * NN + i], zout = acc[3 * NN + i];
    float v = win / (zin + 1e-6f) + wout / (zout + 1e-6f) + selfy[i];
    y[i] = v;
    u32 u = __float_as_uint(v);
    u32 m = (u32)((int)u >> 31) | 0x80000000u;
    u32 k = ~(u ^ m);  // ascending k == descending y
    key[i] = k;
    atomicAdd(&hist[k >> 16], 1u);
}

__global__ __launch_bounds__(1024) void k_scan(const u32* __restrict__ hist, u32* __restrict__ P) {
    __shared__ u32 wsum[16];
    __shared__ u32 woff[16];
    int t = threadIdx.x;
    int base = t * 64;
    u32 hv[64];
#pragma unroll
    for (int i = 0; i < 16; ++i) *(uint4*)&hv[i * 4] = ((const uint4*)(hist + base))[i];
    u32 s = 0;
#pragma unroll
    for (int i = 0; i < 64; ++i) s += hv[i];
    u32 v = s;
    int lane = t & 63;
    for (int off = 1; off < 64; off <<= 1) {
        u32 n = __shfl_up(v, off);
        if (lane >= off) v += n;
    }
    int wid = t >> 6;
    if (lane == 63) wsum[wid] = v;
    __syncthreads();
    if (t == 0) {
        u32 r = 0;
        for (int w = 0; w < 16; ++w) { woff[w] = r; r += wsum[w]; }
    }
    __syncthreads();
    u32 excl = v - s + woff[wid];
#pragma unroll
    for (int i = 0; i < 64; ++i) { P[base + i] = excl; excl += hv[i]; }
    if (t == 1023) P[65536] = excl;
}

__global__ void k_scatter(const u32* __restrict__ key, const u32* __restrict__ P,
                          u32* __restrict__ cnt, u64* __restrict__ S) {
    int i = blockIdx.x * blockDim.x + threadIdx.x;
    if (i >= NN) return;
    u32 k = key[i];
    u32 b = k >> 16;
    u32 pos = P[b] + atomicAdd(&cnt[b], 1u);
    S[pos] = ((u64)k << 16) | (u32)i;
}

__global__ void k_rank(const u32* __restrict__ key, const u32* __restrict__ P,
                       const u64* __restrict__ S, u32* __restrict__ rnk) {
    int i = blockIdx.x * blockDim.x + threadIdx.x;
    if (i >= NN) return;
    u32 k = key[i];
    u32 b = k >> 16;
    u64 me = ((u64)k << 16) | (u32)i;
    u32 st = P[b], en = P[b + 1];
    u32 c = 0;
    for (u32 j = st; j < en; ++j) c += (S[j] < me) ? 1u : 0u;
    rnk[i] = st + c;
}

__global__ void k_bsum(const u32* __restrict__ rnk, u32* __restrict__ bs) {
    __shared__ u32 red[4];
    int i = blockIdx.x * 256 + threadIdx.x;
    u32 v = (i < NN && rnk[i] < KSEL) ? 1u : 0u;
    for (int off = 32; off; off >>= 1) v += __shfl_xor(v, off);
    int lane = threadIdx.x & 63, w = threadIdx.x >> 6;
    if (lane == 0) red[w] = v;
    __syncthreads();
    if (threadIdx.x == 0) bs[blockIdx.x] = red[0] + red[1] + red[2] + red[3];
}

__global__ __launch_bounds__(256) void k_bscan(const u32* __restrict__ bs, u32* __restrict__ bo, int nb) {
    __shared__ u32 ws[4];
    int t = threadIdx.x;
    u32 x = (t < nb) ? bs[t] : 0;
    u32 v = x;
    int lane = t & 63;
    for (int o = 1; o < 64; o <<= 1) { u32 n = __shfl_up(v, o); if (lane >= o) v += n; }
    int w = t >> 6;
    if (lane == 63) ws[w] = v;
    __syncthreads();
    if (t == 0) { u32 r = 0; for (int i = 0; i < 4; ++i) { u32 q = ws[i]; ws[i] = r; r += q; } }
    __syncthreads();
    if (t < nb) bo[t] = v + ws[w] - x;
}

__global__ void k_select(const u32* __restrict__ rnk, const u32* __restrict__ bo,
                         u32* __restrict__ selj, float* __restrict__ out_ids) {
    __shared__ u32 woff[4];
    int t = threadIdx.x;
    int i = blockIdx.x * 256 + t;
    u32 f = (i < NN && rnk[i] < KSEL) ? 1u : 0u;
    u32 v = f;
    int lane = t & 63;
    for (int off = 1; off < 64; off <<= 1) {
        u32 n = __shfl_up(v, off);
        if (lane >= off) v += n;
    }
    int w = t >> 6;
    if (lane == 63) woff[w] = v;
    __syncthreads();
    if (t == 0) {
        u32 r = 0;
        for (int k = 0; k < 4; ++k) { u32 x = woff[k]; woff[k] = r; r += x; }
    }
    __syncthreads();
    if (f) {
        u32 r = bo[blockIdx.x] + woff[w] + (v - f);
        selj[r] = rnk[i];
        out_ids[r] = (float)i;
    }
}

__global__ void k_rows(const u32* __restrict__ selj, const float* __restrict__ h,
                       const float* __restrict__ y, float* __restrict__ out) {
    int row = blockIdx.x * 2 + (threadIdx.x >> 7);
    int c = threadIdx.x & 127;
    if (row >= KSEL) return;
    u32 j = selj[row];
    float yv = y[j];
    float sig = 1.f / (1.f + expf(-yv));
    float v = h[(size_t)j * 128 + c] * sig;
    out[(size_t)row * 128 + c] = v;
}

// ---------------- launcher ----------------

extern "C" void kernel_launch(void* const* d_in, const int* in_sizes, int n_in,
                              void* d_out, int out_size, void* d_ws, size_t ws_size,
                              hipStream_t stream) {
    const float* h    = (const float*)d_in[0];
    const int* src    = (const int*)d_in[1];
    const int* dstp   = (const int*)d_in[2];
    const int* etype  = (const int*)d_in[3];
    const float* Wb   = (const float*)d_in[4];
    const float* coeff = (const float*)d_in[5];
    const float* Wq   = (const float*)d_in[6];
    const float* bq   = (const float*)d_in[7];
    const float* Wk   = (const float*)d_in[8];
    const float* bk   = (const float*)d_in[9];
    const float* Wv   = (const float*)d_in[10];
    const float* bv   = (const float*)d_in[11];

    char* ws = (char*)d_ws;
    size_t off = 0;
    auto alloc = [&](size_t bytes) -> void* {
        void* p = ws + off;
        off = (off + bytes + 255) & ~(size_t)255;
        return p;
    };
    unsigned short* hb   = (unsigned short*)alloc((size_t)NN * 128 * 2);
    unsigned short* Gt   = (unsigned short*)alloc((size_t)640 * 128 * 2);
    unsigned short* q2b  = (unsigned short*)alloc((size_t)NN * 128 * 2);
    unsigned short* a01b = (unsigned short*)alloc((size_t)NN * 256 * 2);
    unsigned short* w0b  = (unsigned short*)alloc((size_t)NN * 128 * 2);
    unsigned short* w1b  = (unsigned short*)alloc((size_t)NN * 128 * 2);
    u64* EP      = (u64*)alloc((size_t)NE * 8);
    u32* eoff    = (u32*)alloc((NB_E + 1) * 4);
    float* bqk   = (float*)alloc(128 * 4);
    float* wvecs = (float*)alloc(644 * 4);
    float* NS    = (float*)alloc((size_t)NN * 4 * 4);
    float* TT    = (float*)alloc((size_t)NN * 4 * 4);
    float* selfy = (float*)alloc((size_t)NN * 4);
    float* y     = (float*)alloc((size_t)NN * 4);
    u32* key     = (u32*)alloc((size_t)NN * 4);
    u64* S       = (u64*)alloc((size_t)NN * 8);
    u32* rnk     = (u32*)alloc((size_t)NN * 4);
    u32* selj    = (u32*)alloc((size_t)KSEL * 4);
    u32* bs      = (u32*)alloc(256 * 4);
    u32* bo      = (u32*)alloc(256 * 4);
    u32* P       = (u32*)alloc(65537 * 4);
    size_t zstart = off;
    float* acc = (float*)alloc((size_t)NN * 4 * 4);
    u32* hist  = (u32*)alloc(65536 * 4);
    u32* cnt   = (u32*)alloc(65536 * 4);
    u32* ecnt  = (u32*)alloc((NB_E + 1) * 4);
    u32* ecnt2 = (u32*)alloc((NB_E + 1) * 4);
    size_t zend = off;
    (void)ws_size; (void)n_in; (void)in_sizes; (void)out_size;

    hipMemsetAsync(ws + zstart, 0, zend - zstart, stream);

    k_cast<<<(NN * 128 / 4 + 255) / 256, 256, 0, stream>>>(h, hb);
    k_wqk<<<128, 128, 0, stream>>>(Wq, Wk, bq, Gt, bqk);
    k_prep<<<(65536 + 641 + 255) / 256, 256, 0, stream>>>(Wb, Wq, bq, bk, Wv, Gt, wvecs);
    k_ehist<<<(NE + 255) / 256, 256, 0, stream>>>(dstp, ecnt);
    k_escan<<<1, 512, 0, stream>>>(ecnt, eoff);
    k_escat<<<(NE + 255) / 256, 256, 0, stream>>>(src, dstp, etype, eoff, ecnt2, EP);
    k_mfma<<<dim3((NN + 127) / 128, 5), 256, 0, stream>>>(hb, Gt, bqk, q2b, a01b, w0b, w1b);
    k_tdot<<<(NN + 3) / 4, 256, 0, stream>>>(q2b, w0b, w1b, TT);
    k_scal<<<(NN * 64 + 255) / 256, 256, 0, stream>>>(h, wvecs, coeff, bv, NS, TT, selfy);
    k_edge<<<NE / 8, 256, 0, stream>>>(a01b, q2b, EP, NS, TT, coeff, bv, acc);
    int nb = (NN + 255) / 256;
    k_y<<<nb, 256, 0, stream>>>(acc, selfy, y, key, hist);
    k_scan<<<1, 1024, 0, stream>>>(hist, P);
    k_scatter<<<nb, 256, 0, stream>>>(key, P, cnt, S);
    k_rank<<<nb, 256, 0, stream>>>(key, P, S, rnk);
    k_bsum<<<nb, 256, 0, stream>>>(rnk, bs);
    k_bscan<<<1, 256, 0, stream>>>(bs, bo, nb);
    float* out = (float*)d_out;
    k_select<<<nb, 256, 0, stream>>>(rnk, bo, selj, out + (size_t)KSEL * 128);
    k_rows<<<(KSEL + 1) / 2, 256, 0, stream>>>(selj, h, y, out);
}

// Round 11
// 395.948 us; speedup vs baseline: 1.9984x; 1.9984x over previous
//
#include <hip/hip_runtime.h>
#include <hip/hip_bf16.h>
#include <math.h>

#define NN 50000
#define NE 500000
#define KSEL 25000

typedef unsigned int u32;
typedef unsigned long long u64;
typedef short bf16x8 __attribute__((ext_vector_type(8)));   // 8 bf16 raw bits (4 VGPRs)
typedef float f32x4 __attribute__((ext_vector_type(4)));

__device__ __forceinline__ unsigned short f2bf(float f) {   // RNE
    u32 u = __float_as_uint(f);
    u32 r = (u + 0x7fffu + ((u >> 16) & 1u)) >> 16;
    return (unsigned short)r;
}
__device__ __forceinline__ float dpair(u32 a, u32 q) {
    float al = __uint_as_float(a << 16), ah = __uint_as_float(a & 0xffff0000u);
    float ql = __uint_as_float(q << 16), qh = __uint_as_float(q & 0xffff0000u);
    return al * ql + ah * qh;
}
__device__ __forceinline__ bf16x8 pack8(float4 a, float4 b) {
    bf16x8 r;
    r[0] = (short)f2bf(a.x); r[1] = (short)f2bf(a.y); r[2] = (short)f2bf(a.z); r[3] = (short)f2bf(a.w);
    r[4] = (short)f2bf(b.x); r[5] = (short)f2bf(b.y); r[6] = (short)f2bf(b.z); r[7] = (short)f2bf(b.w);
    return r;
}

// ---------------- fused weight prep: Wqk GEMM + panel transposes + bqk + wvecs ----------------
// wvecs: wa0[0:128] wa1[128:256] wb0[256:384] wb1[384:512] wkn[512:640] bkbq[640]
__global__ void k_prep2(const float* __restrict__ Wq, const float* __restrict__ Wk,
                        const float* __restrict__ bq, const float* __restrict__ bk,
                        const float* __restrict__ Wv, const float* __restrict__ Wb,
                        unsigned short* __restrict__ Gt, float* __restrict__ bqk,
                        float* __restrict__ wvecs) {
    int idx = blockIdx.x * blockDim.x + threadIdx.x;
    if (idx < 16384) {                       // panel0: Gt[m][k] = Wqk[k][m]
        int k = idx >> 7, m = idx & 127;
        float acc = 0.f;
        for (int c = 0; c < 128; ++c) acc += Wq[c * 128 + k] * Wk[c * 128 + m];
        Gt[(size_t)m * 128 + k] = f2bf(acc);
    } else if (idx < 16384 + 65536) {        // panels 1-4
        int i = idx - 16384;
        int p = i >> 14, rem = i & 16383;
        int c = rem >> 7, k = rem & 127;
        float v;
        if (p == 0)      v = Wb[k * 128 + c];                    // W0a -> panel1
        else if (p == 1) v = Wb[32768 + k * 128 + c];            // W1a -> panel2
        else if (p == 2) v = Wb[16384 + k * 128 + c];            // W0b -> panel3
        else             v = Wb[49152 + k * 128 + c];            // W1b -> panel4
        Gt[(size_t)((p + 1) * 128 + c) * 128 + k] = f2bf(v);
    } else {
        int i = idx - 16384 - 65536;         // 0..768
        if (i < 128) { float b = 0; for (int c = 0; c < 128; ++c) b += bq[c] * Wk[c * 128 + i]; bqk[i] = b; }
        else {
            int j = i - 128;                 // 0..640
            if (j < 128)      { float s = 0; for (int m = 0; m < 128; ++m) s += Wb[j * 128 + m] * Wv[m]; wvecs[j] = s; }
            else if (j < 256) { int q = j - 128; float s = 0; for (int m = 0; m < 128; ++m) s += Wb[32768 + q * 128 + m] * Wv[m]; wvecs[j] = s; }
            else if (j < 384) { int q = j - 256; float s = 0; for (int m = 0; m < 128; ++m) s += Wb[(128 + q) * 128 + m] * Wv[m]; wvecs[j] = s; }
            else if (j < 512) { int q = j - 384; float s = 0; for (int m = 0; m < 128; ++m) s += Wb[32768 + (128 + q) * 128 + m] * Wv[m]; wvecs[j] = s; }
            else if (j < 640) { int q = j - 512; float s = 0; for (int c = 0; c < 128; ++c) s += bk[c] * Wq[c * 128 + q]; wvecs[j] = s; }
            else if (j == 640) { float s = 0; for (int c = 0; c < 128; ++c) s += bk[c] * bq[c]; wvecs[640] = s; }
        }
    }
}

// ---------------- fused node kernel: cast + 5-panel MFMA + t-dots + per-node scalars ----------------
// 391 blocks x 256 thr (4 waves). Wave w owns rows [blk*128 + w*32, +32) for everything.
__global__ __launch_bounds__(256) void k_node(const float* __restrict__ h,
                                              const unsigned short* __restrict__ Gt,
                                              const float* __restrict__ bqk,
                                              const float* __restrict__ wvecs,
                                              const float* __restrict__ coeff,
                                              const float* __restrict__ bvp,
                                              unsigned short* __restrict__ q2b,
                                              unsigned short* __restrict__ a01b,
                                              float* __restrict__ NS, float* __restrict__ TT,
                                              float* __restrict__ selfy) {
    int t = threadIdx.x;
    int w = t >> 6, l = t & 63;
    int lr = l & 15, lg = l >> 4;
    int rowbase = blockIdx.x * 128 + w * 32;

    // ---- load A fragments (f32 -> bf16) + per-node scalar dot partials ----
    bf16x8 afr[2][4];
    float ns[2][5];
#pragma unroll
    for (int rt = 0; rt < 2; ++rt)
#pragma unroll
        for (int c = 0; c < 5; ++c) ns[rt][c] = 0.f;

#pragma unroll
    for (int kk = 0; kk < 4; ++kk) {
        float4 wvA[5], wvB[5];
#pragma unroll
        for (int c = 0; c < 5; ++c) {
            const float* wv = wvecs + c * 128 + kk * 32 + lg * 8;
            wvA[c] = *(const float4*)wv;
            wvB[c] = *(const float4*)(wv + 4);
        }
#pragma unroll
        for (int rt = 0; rt < 2; ++rt) {
            int row = rowbase + rt * 16 + lr;
            if (row >= NN) row = NN - 1;    // clamp; all stores guarded
            const float* hp = h + (size_t)row * 128 + kk * 32 + lg * 8;
            float4 a = *(const float4*)hp;
            float4 b = *(const float4*)(hp + 4);
#pragma unroll
            for (int c = 0; c < 5; ++c) {
                ns[rt][c] += a.x * wvA[c].x + a.y * wvA[c].y + a.z * wvA[c].z + a.w * wvA[c].w +
                             b.x * wvB[c].x + b.y * wvB[c].y + b.z * wvB[c].z + b.w * wvB[c].w;
            }
            afr[rt][kk] = pack8(a, b);
        }
    }
    // reduce ns over the 4 lanes sharing a row (l, l^16, l^32, l^48)
#pragma unroll
    for (int rt = 0; rt < 2; ++rt)
#pragma unroll
        for (int c = 0; c < 5; ++c) {
            ns[rt][c] += __shfl_xor(ns[rt][c], 16);
            ns[rt][c] += __shfl_xor(ns[rt][c], 32);
        }
    if (lg == 0) {
        float c40 = coeff[8], c41 = coeff[9], bv = bvp[0], bkbq = wvecs[640];
#pragma unroll
        for (int rt = 0; rt < 2; ++rt) {
            int row = rowbase + rt * 16 + lr;
            if (row < NN) {
                NS[(size_t)row * 4 + 0] = ns[rt][0];
                NS[(size_t)row * 4 + 1] = ns[rt][1];
                NS[(size_t)row * 4 + 2] = ns[rt][2];
                NS[(size_t)row * 4 + 3] = ns[rt][3];
                TT[(size_t)row * 4 + 2] = ns[rt][4] + bkbq;
                selfy[row] = c40 * (ns[rt][0] + ns[rt][2]) + c41 * (ns[rt][1] + ns[rt][3]) + bv;
            }
        }
    }

    f32x4 acc[2][8];
    f32x4 q2k[2][8];

    // ---- panel 0: q2 (keep f32 in regs for t-dots) ----
#pragma unroll
    for (int ct = 0; ct < 8; ++ct) {
        acc[0][ct] = (f32x4){0.f, 0.f, 0.f, 0.f};
        acc[1][ct] = (f32x4){0.f, 0.f, 0.f, 0.f};
#pragma unroll
        for (int kk = 0; kk < 4; ++kk) {
            bf16x8 bfr = *reinterpret_cast<const bf16x8*>(Gt + (size_t)(ct * 16 + lr) * 128 + kk * 32 + lg * 8);
            acc[0][ct] = __builtin_amdgcn_mfma_f32_16x16x32_bf16(afr[0][kk], bfr, acc[0][ct], 0, 0, 0);
            acc[1][ct] = __builtin_amdgcn_mfma_f32_16x16x32_bf16(afr[1][kk], bfr, acc[1][ct], 0, 0, 0);
        }
    }
#pragma unroll
    for (int rt = 0; rt < 2; ++rt)
#pragma unroll
        for (int ct = 0; ct < 8; ++ct) {
            float bb = bqk[ct * 16 + lr];
#pragma unroll
            for (int r = 0; r < 4; ++r) {
                int row = rowbase + rt * 16 + lg * 4 + r;
                float v = acc[rt][ct][r] + bb;
                q2k[rt][ct][r] = v;
                if (row < NN) q2b[(size_t)row * 128 + ct * 16 + lr] = f2bf(v);
            }
        }

    // ---- panels 1,2: a0 | a1 ----
#pragma unroll
    for (int pn = 1; pn <= 2; ++pn) {
#pragma unroll
        for (int ct = 0; ct < 8; ++ct) {
            acc[0][ct] = (f32x4){0.f, 0.f, 0.f, 0.f};
            acc[1][ct] = (f32x4){0.f, 0.f, 0.f, 0.f};
#pragma unroll
            for (int kk = 0; kk < 4; ++kk) {
                bf16x8 bfr = *reinterpret_cast<const bf16x8*>(Gt + (size_t)(pn * 128 + ct * 16 + lr) * 128 + kk * 32 + lg * 8);
                acc[0][ct] = __builtin_amdgcn_mfma_f32_16x16x32_bf16(afr[0][kk], bfr, acc[0][ct], 0, 0, 0);
                acc[1][ct] = __builtin_amdgcn_mfma_f32_16x16x32_bf16(afr[1][kk], bfr, acc[1][ct], 0, 0, 0);
            }
        }
        int cbase = (pn == 1) ? 0 : 128;
#pragma unroll
        for (int rt = 0; rt < 2; ++rt)
#pragma unroll
            for (int ct = 0; ct < 8; ++ct)
#pragma unroll
                for (int r = 0; r < 4; ++r) {
                    int row = rowbase + rt * 16 + lg * 4 + r;
                    if (row < NN) a01b[(size_t)row * 256 + cbase + ct * 16 + lr] = f2bf(acc[rt][ct][r]);
                }
    }

    // ---- panels 3,4: w0,w1 — consumed in-register by t-dots, never stored ----
#pragma unroll
    for (int pn = 3; pn <= 4; ++pn) {
#pragma unroll
        for (int ct = 0; ct < 8; ++ct) {
            acc[0][ct] = (f32x4){0.f, 0.f, 0.f, 0.f};
            acc[1][ct] = (f32x4){0.f, 0.f, 0.f, 0.f};
#pragma unroll
            for (int kk = 0; kk < 4; ++kk) {
                bf16x8 bfr = *reinterpret_cast<const bf16x8*>(Gt + (size_t)(pn * 128 + ct * 16 + lr) * 128 + kk * 32 + lg * 8);
                acc[0][ct] = __builtin_amdgcn_mfma_f32_16x16x32_bf16(afr[0][kk], bfr, acc[0][ct], 0, 0, 0);
                acc[1][ct] = __builtin_amdgcn_mfma_f32_16x16x32_bf16(afr[1][kk], bfr, acc[1][ct], 0, 0, 0);
            }
        }
        float tp[2][4];
#pragma unroll
        for (int rt = 0; rt < 2; ++rt)
#pragma unroll
            for (int r = 0; r < 4; ++r) {
                float s = 0.f;
#pragma unroll
                for (int ct = 0; ct < 8; ++ct) s += q2k[rt][ct][r] * acc[rt][ct][r];
                s += __shfl_xor(s, 1);
                s += __shfl_xor(s, 2);
                s += __shfl_xor(s, 4);
                s += __shfl_xor(s, 8);
                tp[rt][r] = s;
            }
        if (lr == 0) {
#pragma unroll
            for (int rt = 0; rt < 2; ++rt)
#pragma unroll
                for (int r = 0; r < 4; ++r) {
                    int row = rowbase + rt * 16 + lg * 4 + r;
                    if (row < NN) TT[(size_t)row * 4 + (pn - 3)] = tp[rt][r];
                }
        }
    }
}

// ---------------- edge kernel: bf16, 2 edges/wave, 8-lane dot groups (round-7 proven) ----------------
__global__ __launch_bounds__(256) void k_edge(const unsigned short* __restrict__ a01b,
                                              const unsigned short* __restrict__ q2b,
                                              const int* __restrict__ src, const int* __restrict__ dst,
                                              const int* __restrict__ et,
                                              const float* __restrict__ NS, const float* __restrict__ TT,
                                              const float* __restrict__ coeff, const float* __restrict__ bvp,
                                              float* __restrict__ acc) {
    int tid = threadIdx.x;
    int e = blockIdx.x * 8 + (tid >> 5);        // 8 edges per 256-thr block (exact: NE/8 blocks)
    int lane = tid & 63;
    int l5 = tid & 31;
    int g = l5 >> 3, sub = l5 & 7;              // 4 dot groups of 8 lanes per edge
    int s = src[e], d = dst[e];
    int r1 = (g < 2) ? s : d;
    int r2 = (g < 2) ? d : s;
    const u32* ap = (const u32*)(a01b + (size_t)r1 * 256 + (g & 1) * 128) + sub * 8;
    const u32* qp = (const u32*)(q2b + (size_t)r2 * 128) + sub * 8;
    uint4 A0 = *(const uint4*)ap, A1 = *(const uint4*)(ap + 4);
    uint4 Q0 = *(const uint4*)qp, Q1 = *(const uint4*)(qp + 4);
    float p = dpair(A0.x, Q0.x) + dpair(A0.y, Q0.y) + dpair(A0.z, Q0.z) + dpair(A0.w, Q0.w) +
              dpair(A1.x, Q1.x) + dpair(A1.y, Q1.y) + dpair(A1.z, Q1.z) + dpair(A1.w, Q1.w);
    p += __shfl_xor(p, 4);
    p += __shfl_xor(p, 2);
    p += __shfl_xor(p, 1);
    float mate = __shfl(p, (lane + 8) & 63);
    if ((l5 & 15) == 0) {
        bool outdir = (l5 == 16);
        int agg = outdir ? s : d;
        int oth = outdir ? d : s;
        int ety = et[e];
        float c0 = coeff[ety * 2], c1 = coeff[ety * 2 + 1];
        float4 tt = *(const float4*)(TT + (size_t)agg * 4);
        float4 nsO = *(const float4*)(NS + (size_t)oth * 4);
        float4 nsA = *(const float4*)(NS + (size_t)agg * 4);
        float raw = c0 * (p + tt.x) + c1 * (mate + tt.y) + tt.z;
        float xc = fminf(fmaxf(raw * 0.08838834764831845f, -10.f), 10.f);
        float sc = expf(xc);
        float nv = c0 * (nsO.x + nsA.z) + c1 * (nsO.y + nsA.w) + bvp[0];
        float* wacc = acc + (size_t)(outdir ? 2 : 0) * NN;
        float* zacc = acc + (size_t)(outdir ? 3 : 1) * NN;
        atomicAdd(&wacc[agg], sc * nv);
        atomicAdd(&zacc[agg], sc);
    }
}

// ---------------- y, key, ranking, selection, output ----------------

__global__ void k_y(const float* __restrict__ acc, const float* __restrict__ selfy,
                    float* __restrict__ y, u32* __restrict__ key, u32* __restrict__ hist) {
    int i = blockIdx.x * blockDim.x + threadIdx.x;
    if (i >= NN) return;
    float win = acc[i], zin = acc[NN + i], wout = acc[2 * NN + i], zout = acc[3 * NN + i];
    float v = win / (zin + 1e-6f) + wout / (zout + 1e-6f) + selfy[i];
    y[i] = v;
    u32 u = __float_as_uint(v);
    u32 m = (u32)((int)u >> 31) | 0x80000000u;
    u32 k = ~(u ^ m);  // ascending k == descending y
    key[i] = k;
    atomicAdd(&hist[k >> 16], 1u);
}

__global__ __launch_bounds__(1024) void k_scan(const u32* __restrict__ hist, u32* __restrict__ P) {
    __shared__ u32 wsum[16];
    __shared__ u32 woff[16];
    int t = threadIdx.x;
    int base = t * 64;
    u32 hv[64];
#pragma unroll
    for (int i = 0; i < 16; ++i) *(uint4*)&hv[i * 4] = ((const uint4*)(hist + base))[i];
    u32 s = 0;
#pragma unroll
    for (int i = 0; i < 64; ++i) s += hv[i];
    u32 v = s;
    int lane = t & 63;
    for (int off = 1; off < 64; off <<= 1) {
        u32 n = __shfl_up(v, off);
        if (lane >= off) v += n;
    }
    int wid = t >> 6;
    if (lane == 63) wsum[wid] = v;
    __syncthreads();
    if (t == 0) {
        u32 r = 0;
        for (int w = 0; w < 16; ++w) { woff[w] = r; r += wsum[w]; }
    }
    __syncthreads();
    u32 excl = v - s + woff[wid];
#pragma unroll
    for (int i = 0; i < 64; ++i) { P[base + i] = excl; excl += hv[i]; }
    if (t == 1023) P[65536] = excl;
}

__global__ void k_scatter(const u32* __restrict__ key, const u32* __restrict__ P,
                          u32* __restrict__ cnt, u64* __restrict__ S) {
    int i = blockIdx.x * blockDim.x + threadIdx.x;
    if (i >= NN) return;
    u32 k = key[i];
    u32 b = k >> 16;
    u32 pos = P[b] + atomicAdd(&cnt[b], 1u);
    S[pos] = ((u64)k << 16) | (u32)i;
}

// rank + per-block selected-count (fused bsum)
__global__ void k_rank(const u32* __restrict__ key, const u32* __restrict__ P,
                       const u64* __restrict__ S, u32* __restrict__ rnk, u32* __restrict__ bs) {
    __shared__ u32 red[4];
    int i = blockIdx.x * 256 + threadIdx.x;
    u32 f = 0;
    if (i < NN) {
        u32 k = key[i];
        u32 b = k >> 16;
        u64 me = ((u64)k << 16) | (u32)i;
        u32 st = P[b], en = P[b + 1];
        u32 c = 0;
        for (u32 j = st; j < en; ++j) c += (S[j] < me) ? 1u : 0u;
        u32 r = st + c;
        rnk[i] = r;
        f = (r < KSEL) ? 1u : 0u;
    }
    for (int off = 32; off; off >>= 1) f += __shfl_xor(f, off);
    int lane = threadIdx.x & 63, w = threadIdx.x >> 6;
    if (lane == 0) red[w] = f;
    __syncthreads();
    if (threadIdx.x == 0) bs[blockIdx.x] = red[0] + red[1] + red[2] + red[3];
}

// select with inline block-count scan (fused bscan)
__global__ __launch_bounds__(256) void k_select(const u32* __restrict__ rnk, const u32* __restrict__ bs,
                                                u32* __restrict__ selj, float* __restrict__ out_ids, int nb) {
    __shared__ u32 sc[256];
    __shared__ u32 aux[4];
    __shared__ u32 aux2[4];
    int t = threadIdx.x;
    int lane = t & 63, w = t >> 6;
    // exclusive scan of bs -> sc
    u32 x = (t < nb) ? bs[t] : 0;
    u32 v = x;
    for (int o = 1; o < 64; o <<= 1) { u32 n = __shfl_up(v, o); if (lane >= o) v += n; }
    if (lane == 63) aux[w] = v;
    __syncthreads();
    if (t == 0) { u32 r = 0; for (int k = 0; k < 4; ++k) { u32 q = aux[k]; aux[k] = r; r += q; } }
    __syncthreads();
    sc[t] = v + aux[w] - x;
    __syncthreads();
    u32 base = sc[blockIdx.x];
    // per-block selection scan
    int i = blockIdx.x * 256 + t;
    u32 f = (i < NN && rnk[i] < KSEL) ? 1u : 0u;
    u32 vv = f;
    for (int o = 1; o < 64; o <<= 1) { u32 n = __shfl_up(vv, o); if (lane >= o) vv += n; }
    if (lane == 63) aux2[w] = vv;
    __syncthreads();
    if (t == 0) { u32 r = 0; for (int k = 0; k < 4; ++k) { u32 q = aux2[k]; aux2[k] = r; r += q; } }
    __syncthreads();
    if (f) {
        u32 r = base + aux2[w] + (vv - f);
        selj[r] = rnk[i];
        out_ids[r] = (float)i;
    }
}

__global__ void k_rows(const u32* __restrict__ selj, const float* __restrict__ h,
                       const float* __restrict__ y, float* __restrict__ out) {
    int row = blockIdx.x * 2 + (threadIdx.x >> 7);
    int c = threadIdx.x & 127;
    if (row >= KSEL) return;
    u32 j = selj[row];
    float yv = y[j];
    float sig = 1.f / (1.f + expf(-yv));
    float v = h[(size_t)j * 128 + c] * sig;
    out[(size_t)row * 128 + c] = v;
}

// ---------------- launcher ----------------

extern "C" void kernel_launch(void* const* d_in, const int* in_sizes, int n_in,
                              void* d_out, int out_size, void* d_ws, size_t ws_size,
                              hipStream_t stream) {
    const float* h    = (const float*)d_in[0];
    const int* src    = (const int*)d_in[1];
    const int* dstp   = (const int*)d_in[2];
    const int* etype  = (const int*)d_in[3];
    const float* Wb   = (const float*)d_in[4];
    const float* coeff = (const float*)d_in[5];
    const float* Wq   = (const float*)d_in[6];
    const float* bq   = (const float*)d_in[7];
    const float* Wk   = (const float*)d_in[8];
    const float* bk   = (const float*)d_in[9];
    const float* Wv   = (const float*)d_in[10];
    const float* bv   = (const float*)d_in[11];

    char* ws = (char*)d_ws;
    size_t off = 0;
    auto alloc = [&](size_t bytes) -> void* {
        void* p = ws + off;
        off = (off + bytes + 255) & ~(size_t)255;
        return p;
    };
    unsigned short* Gt   = (unsigned short*)alloc((size_t)640 * 128 * 2);
    unsigned short* q2b  = (unsigned short*)alloc((size_t)NN * 128 * 2);
    unsigned short* a01b = (unsigned short*)alloc((size_t)NN * 256 * 2);
    float* bqk   = (float*)alloc(128 * 4);
    float* wvecs = (float*)alloc(644 * 4);
    float* NS    = (float*)alloc((size_t)NN * 4 * 4);
    float* TT    = (float*)alloc((size_t)NN * 4 * 4);
    float* selfy = (float*)alloc((size_t)NN * 4);
    float* y     = (float*)alloc((size_t)NN * 4);
    u32* key     = (u32*)alloc((size_t)NN * 4);
    u64* S       = (u64*)alloc((size_t)NN * 8);
    u32* rnk     = (u32*)alloc((size_t)NN * 4);
    u32* selj    = (u32*)alloc((size_t)KSEL * 4);
    u32* bs      = (u32*)alloc(256 * 4);
    u32* P       = (u32*)alloc(65537 * 4);
    size_t zstart = off;
    float* acc = (float*)alloc((size_t)NN * 4 * 4);
    u32* hist  = (u32*)alloc(65536 * 4);
    u32* cnt   = (u32*)alloc(65536 * 4);
    size_t zend = off;
    (void)ws_size; (void)n_in; (void)in_sizes; (void)out_size;

    hipMemsetAsync(ws + zstart, 0, zend - zstart, stream);

    k_prep2<<<(16384 + 65536 + 769 + 255) / 256, 256, 0, stream>>>(Wq, Wk, bq, bk, Wv, Wb, Gt, bqk, wvecs);
    k_node<<<(NN + 127) / 128, 256, 0, stream>>>(h, Gt, bqk, wvecs, coeff, bv, q2b, a01b, NS, TT, selfy);
    k_edge<<<NE / 8, 256, 0, stream>>>(a01b, q2b, src, dstp, etype, NS, TT, coeff, bv, acc);
    int nb = (NN + 255) / 256;
    k_y<<<nb, 256, 0, stream>>>(acc, selfy, y, key, hist);
    k_scan<<<1, 1024, 0, stream>>>(hist, P);
    k_scatter<<<nb, 256, 0, stream>>>(key, P, cnt, S);
    k_rank<<<nb, 256, 0, stream>>>(key, P, S, rnk, bs);
    float* out = (float*)d_out;
    k_select<<<nb, 256, 0, stream>>>(rnk, bs, selj, out + (size_t)KSEL * 128, nb);
    k_rows<<<(KSEL + 1) / 2, 256, 0, stream>>>(selj, h, y, out);
}